// Round 5
// baseline (679.974 us; speedup 1.0000x reference)
//
#include <hip/hip_runtime.h>
#include <hip/hip_bf16.h>

// RGCN: out = hetero(relu(hetero(x, W1,b1)), W2,b2)
// hetero(x) = sum_r [ Din_r^-1/2 A_r_sl Dout_r^-1/2 (x @ W_r) ] + sum_r b_r
// KEY RESTRUCTURE (round 5): aggregation commutes with @W_r, so all three
// relations gather from the SAME feature buffer in one pass:
//   Zcat[n] = [ rs_in_r[n] * sum_{e->n in rel r} rs_out_r[s_e] * feat[s_e] ]_r  (N x 384)
//   H = bsum1 + Zcat @ reshape(W1, 384x128)   (stacked-W layout == W1 memory order)
// This cuts random-gather fabric traffic ~3x (each XCD fetches the 25.6 MB
// feature buffer once, not once per relation).
// CSR build: two-pass radix partition, zero global atomics (round-3 lesson:
// device-scope atomicAdd costs ~32B fabric write each; LDS atomics are free).

constexpr int N   = 50000;
constexpr int R   = 3;
constexpr int IN  = 128;
constexpr int HID = 128;
constexpr int OUT = 64;
constexpr int M   = R * N;                 // 150000 (rel,node) slots
constexpr int BK  = 1024;                  // keys per bucket
constexpr int NBKT = (M + BK - 1) / BK;    // 147 buckets
constexpr int CHUNK = 8192;                // edges per partition block

// ---- bias sums: bsum1[j] = sum_r b1[r][j], bsum2 likewise ----
__global__ void bsum_kernel(const float* __restrict__ b1, const float* __restrict__ b2,
                            float* __restrict__ bsum1, float* __restrict__ bsum2) {
    int t = threadIdx.x;
    if (t < HID) bsum1[t] = b1[t] + b1[HID + t] + b1[2 * HID + t];
    if (t < OUT) bsum2[t] = b2[t] + b2[OUT + t] + b2[2 * OUT + t];
}

// ---- P1: coarse bucket histograms per edge-chunk (dst-keyed and src-keyed) ----
__global__ __launch_bounds__(256) void p1_kernel(const int* __restrict__ src,
                                                 const int* __restrict__ dst,
                                                 int E, int RE, int nb,
                                                 int* __restrict__ bh) {
    __shared__ int hd[NBKT], hs[NBKT];
    for (int i = threadIdx.x; i < NBKT; i += 256) { hd[i] = 0; hs[i] = 0; }
    __syncthreads();
    int beg = blockIdx.x * CHUNK, end = min(RE, beg + CHUNK);
    for (int g = beg + (int)threadIdx.x; g < end; g += 256) {
        int rb = ((g >= E) + (g >= 2 * E)) * N;
        atomicAdd(&hd[(rb + dst[g]) >> 10], 1);
        atomicAdd(&hs[(rb + src[g]) >> 10], 1);
    }
    __syncthreads();
    for (int i = threadIdx.x; i < NBKT; i += 256) {
        bh[i * nb + blockIdx.x] = hd[i];                 // [bucket][block], d-half
        bh[(NBKT + i) * nb + blockIdx.x] = hs[i];        // s-half
    }
}

// ---- generic 3-stage exclusive scan over L ints ----
__global__ void scan1_kernel(const int* __restrict__ in, int* __restrict__ out,
                             int* __restrict__ partials, int L) {
    __shared__ int lds[1024];
    int t = threadIdx.x;
    int idx = blockIdx.x * 1024 + t;
    int v = (idx < L) ? in[idx] : 0;
    lds[t] = v;
    __syncthreads();
    for (int off = 1; off < 1024; off <<= 1) {
        int u = (t >= off) ? lds[t - off] : 0;
        __syncthreads();
        lds[t] += u;
        __syncthreads();
    }
    if (idx < L) out[idx] = lds[t] - v;
    if (t == 1023) partials[blockIdx.x] = lds[1023];
}

__global__ void scan2_kernel(int* __restrict__ partials, int nb1) {
    __shared__ int lds[256];
    int t = threadIdx.x;
    int v = (t < nb1) ? partials[t] : 0;
    lds[t] = v;
    __syncthreads();
    for (int off = 1; off < 256; off <<= 1) {
        int u = (t >= off) ? lds[t - off] : 0;
        __syncthreads();
        lds[t] += u;
        __syncthreads();
    }
    if (t < nb1) partials[t] = lds[t] - v;
}

__global__ void scan3_kernel(int* __restrict__ out, const int* __restrict__ partials, int L) {
    int i = blockIdx.x * 256 + threadIdx.x;
    if (i < L) out[i] += partials[i >> 10];
}

// ---- P3: scatter edges into bucket-sorted buffers via LDS cursors ----
// ebd[pos] = (src<<10)|(key&1023); ebs[pos] = key&1023
__global__ __launch_bounds__(256) void p3_kernel(const int* __restrict__ src,
                                                 const int* __restrict__ dst,
                                                 int E, int RE, int nb,
                                                 const int* __restrict__ scanv,
                                                 int* __restrict__ ebd,
                                                 int* __restrict__ ebs) {
    __shared__ int cd[NBKT], cs[NBKT];
    for (int i = threadIdx.x; i < NBKT; i += 256) {
        cd[i] = scanv[i * nb + blockIdx.x];
        cs[i] = scanv[(NBKT + i) * nb + blockIdx.x] - RE;
    }
    __syncthreads();
    int beg = blockIdx.x * CHUNK, end = min(RE, beg + CHUNK);
    for (int g = beg + (int)threadIdx.x; g < end; g += 256) {
        int rb = ((g >= E) + (g >= 2 * E)) * N;
        int s  = src[g];
        int kd = rb + dst[g];
        int pd = atomicAdd(&cd[kd >> 10], 1);
        ebd[pd] = (s << 10) | (kd & 1023);
        int ks = rb + s;
        int ps = atomicAdd(&cs[ks >> 10], 1);
        ebs[ps] = ks & 1023;
    }
}

// ---- PB: per bucket — exact histogram -> row_ptr/rs, then CSR scatter ----
__global__ __launch_bounds__(1024) void pb_kernel(const int* __restrict__ scanv, int nb, int RE,
                                                  const int* __restrict__ ebd,
                                                  const int* __restrict__ ebs,
                                                  int* __restrict__ row_ptr,
                                                  float* __restrict__ rs_in,
                                                  float* __restrict__ rs_out,
                                                  int* __restrict__ esrc) {
    __shared__ int cnt[BK];
    __shared__ int cur[BK];
    int t = threadIdx.x;
    bool dside = blockIdx.x < NBKT;
    int k = dside ? blockIdx.x : blockIdx.x - NBKT;
    int half = dside ? 0 : NBKT;
    int segbeg = scanv[(half + k) * nb];
    int segend = (k == NBKT - 1) ? (dside ? RE : 2 * RE) : scanv[(half + k + 1) * nb];
    if (!dside) { segbeg -= RE; segend -= RE; }
    cnt[t] = 0;
    __syncthreads();
    const int* __restrict__ eb = dside ? ebd : ebs;
    for (int e = segbeg + t; e < segend; e += 1024)
        atomicAdd(&cnt[eb[e] & 1023], 1);
    __syncthreads();
    int slot = k * BK + t;
    int c = cnt[t];
    if (dside) {
        cur[t] = c;
        __syncthreads();
        for (int off = 1; off < 1024; off <<= 1) {
            int u = (t >= off) ? cur[t - off] : 0;
            __syncthreads();
            cur[t] += u;
            __syncthreads();
        }
        int excl = cur[t] - c;
        if (slot < M) {
            row_ptr[slot] = segbeg + excl;
            rs_in[slot] = rsqrtf((float)(c + 1));   // +1 self-loop
        }
        if (blockIdx.x == NBKT - 1 && t == 0) row_ptr[M] = RE;
        __syncthreads();
        cur[t] = segbeg + excl;
        __syncthreads();
        for (int e = segbeg + t; e < segend; e += 1024) {
            int v = eb[e];
            int pos = atomicAdd(&cur[v & 1023], 1);
            esrc[pos] = v >> 10;
        }
    } else {
        if (slot < M) rs_out[slot] = rsqrtf((float)(c + 1));
    }
}

// ---- fused 3-relation gather: Zcat[n][r*128+c] = rs_in_r[n] * sum_e rs_out_r[s]*feat[s][c]
// (+ self-loop). One wave per node; feat rows are float2/lane; optional relu on load.
template <bool RELU>
__global__ __launch_bounds__(256) void gather_kernel(const float* __restrict__ Xin,
                                                     const float* __restrict__ rs_in,
                                                     const float* __restrict__ rs_out,
                                                     const int* __restrict__ row_ptr,
                                                     const int* __restrict__ esrc,
                                                     float* __restrict__ Z) {
    int n = blockIdx.x * 4 + (threadIdx.x >> 6);
    if (n >= N) return;
    int lane = threadIdx.x & 63;
    const float2* X2 = (const float2*)Xin;
    float2 xn = X2[(long)n * 64 + lane];
    if (RELU) { xn.x = fmaxf(xn.x, 0.f); xn.y = fmaxf(xn.y, 0.f); }
    float2* Z2 = (float2*)Z;
#pragma unroll
    for (int r = 0; r < R; r++) {
        int key = r * N + n;
        const float* __restrict__ rso = rs_out + r * N;
        float ax = 0.f, ay = 0.f;
        int beg = row_ptr[key], end = row_ptr[key + 1];
        int e = beg;
        for (; e + 4 <= end; e += 4) {
            int s0 = esrc[e], s1 = esrc[e + 1], s2 = esrc[e + 2], s3 = esrc[e + 3];
            float c0 = rso[s0], c1 = rso[s1], c2 = rso[s2], c3 = rso[s3];
            float2 y0 = X2[(long)s0 * 64 + lane];
            float2 y1 = X2[(long)s1 * 64 + lane];
            float2 y2 = X2[(long)s2 * 64 + lane];
            float2 y3 = X2[(long)s3 * 64 + lane];
            if (RELU) {
                y0.x = fmaxf(y0.x, 0.f); y0.y = fmaxf(y0.y, 0.f);
                y1.x = fmaxf(y1.x, 0.f); y1.y = fmaxf(y1.y, 0.f);
                y2.x = fmaxf(y2.x, 0.f); y2.y = fmaxf(y2.y, 0.f);
                y3.x = fmaxf(y3.x, 0.f); y3.y = fmaxf(y3.y, 0.f);
            }
            ax += c0 * y0.x + c1 * y1.x + c2 * y2.x + c3 * y3.x;
            ay += c0 * y0.y + c1 * y1.y + c2 * y2.y + c3 * y3.y;
        }
        for (; e < end; e++) {
            int s = esrc[e];
            float c = rso[s];
            float2 y = X2[(long)s * 64 + lane];
            if (RELU) { y.x = fmaxf(y.x, 0.f); y.y = fmaxf(y.y, 0.f); }
            ax += c * y.x; ay += c * y.y;
        }
        float cn = rso[n];                    // self-loop
        ax += cn * xn.x; ay += cn * xn.y;
        float ri = rs_in[key];
        Z2[(long)n * 192 + r * 64 + lane] = make_float2(ri * ax, ri * ay);
    }
}

// ---- fp32 GEMM: Hout[N,WC] = bias[WC] + Z[N,384] @ Wall[384,WC] ----
// 64x64 tile, K staged in 3 chunks of 128.
template <int WC>
__global__ __launch_bounds__(256) void gemmZ_kernel(const float* __restrict__ Z,
                                                    const float* __restrict__ Wall,
                                                    const float* __restrict__ bias,
                                                    float* __restrict__ Hout) {
    __shared__ float sX[64 * 132];
    __shared__ float sW[128 * 64];
    int tid = threadIdx.x;
    int m0  = blockIdx.x * 64;
    int c0  = blockIdx.y * 64;
    int tx = tid & 15;
    int ty = tid >> 4;
    float4 acc[4];
#pragma unroll
    for (int i = 0; i < 4; i++) acc[i] = make_float4(0.f, 0.f, 0.f, 0.f);

    const float4* Z4 = (const float4*)Z;
    for (int kc = 0; kc < 384; kc += 128) {
        for (int j = tid; j < 64 * 32; j += 256) {
            int row = j >> 5, c4 = j & 31;
            float4 v = make_float4(0.f, 0.f, 0.f, 0.f);
            if (m0 + row < N) v = Z4[(long)(m0 + row) * 96 + (kc >> 2) + c4];
            *(float4*)&sX[row * 132 + c4 * 4] = v;
        }
        for (int j = tid; j < 128 * 16; j += 256) {
            int k = j >> 4, c4 = j & 15;
            *(float4*)&sW[k * 64 + c4 * 4] = *(const float4*)&Wall[(long)(kc + k) * WC + c0 + c4 * 4];
        }
        __syncthreads();
        for (int k = 0; k < 128; k += 4) {
            float4 w0 = *(float4*)&sW[(k + 0) * 64 + tx * 4];
            float4 w1 = *(float4*)&sW[(k + 1) * 64 + tx * 4];
            float4 w2 = *(float4*)&sW[(k + 2) * 64 + tx * 4];
            float4 w3 = *(float4*)&sW[(k + 3) * 64 + tx * 4];
#pragma unroll
            for (int i = 0; i < 4; i++) {
                float4 xv = *(float4*)&sX[(ty * 4 + i) * 132 + k];
                acc[i].x += xv.x * w0.x + xv.y * w1.x + xv.z * w2.x + xv.w * w3.x;
                acc[i].y += xv.x * w0.y + xv.y * w1.y + xv.z * w2.y + xv.w * w3.y;
                acc[i].z += xv.x * w0.z + xv.y * w1.z + xv.z * w2.z + xv.w * w3.z;
                acc[i].w += xv.x * w0.w + xv.y * w1.w + xv.z * w2.w + xv.w * w3.w;
            }
        }
        __syncthreads();
    }
    float4 b4 = *(const float4*)&bias[c0 + tx * 4];
#pragma unroll
    for (int i = 0; i < 4; i++) {
        int row = m0 + ty * 4 + i;
        if (row < N) {
            float4 a = acc[i];
            a.x += b4.x; a.y += b4.y; a.z += b4.z; a.w += b4.w;
            *(float4*)&Hout[(long)row * WC + c0 + tx * 4] = a;
        }
    }
}

extern "C" void kernel_launch(void* const* d_in, const int* in_sizes, int n_in,
                              void* d_out, int out_size, void* d_ws, size_t ws_size,
                              hipStream_t stream) {
    const float* x  = (const float*)d_in[0];
    const int*  src = (const int*)d_in[1];
    const int*  dst = (const int*)d_in[2];
    const float* W1 = (const float*)d_in[3];   // [3][128][128] == [384][128]
    const float* b1 = (const float*)d_in[4];
    const float* W2 = (const float*)d_in[5];   // [3][128][64]  == [384][64]
    const float* b2 = (const float*)d_in[6];
    float* out = (float*)d_out;
    const int E  = in_sizes[1] / R;
    const int RE = in_sizes[1];
    const int nb = (RE + CHUNK - 1) / CHUNK;      // edge chunks (293)
    const int L  = 2 * NBKT * nb;                 // scan length (~86k)
    const int nb1 = (L + 1023) / 1024;            // scan1 blocks (<=256)

    char* ws = (char*)d_ws;
    size_t off = 0;
    auto alloc = [&](size_t bytes) -> void* {
        void* p = ws + off;
        off += (bytes + 255) & ~(size_t)255;
        return p;
    };
    float* bsum1    = (float*)alloc(HID * 4);
    float* bsum2    = (float*)alloc(OUT * 4);
    float* rs_in    = (float*)alloc((size_t)M * 4);
    float* rs_out   = (float*)alloc((size_t)M * 4);
    int*   row_ptr  = (int*)alloc((size_t)(M + 1) * 4);
    int*   bh       = (int*)alloc((size_t)L * 4);
    int*   scanv    = (int*)alloc((size_t)L * 4);
    int*   partials = (int*)alloc((size_t)nb1 * 4);
    int*   esrc     = (int*)alloc((size_t)RE * 4);
    // region A: ebd+ebs (19.2MB) during build, Zcat (76.8MB) afterwards
    char*  regA     = (char*)alloc((size_t)N * 384 * 4);
    int*   ebd      = (int*)regA;
    int*   ebs      = (int*)(regA + (size_t)RE * 4);
    float* Z        = (float*)regA;
    float* H        = (float*)alloc((size_t)N * HID * 4);

    bsum_kernel<<<1, 128, 0, stream>>>(b1, b2, bsum1, bsum2);
    p1_kernel<<<nb, 256, 0, stream>>>(src, dst, E, RE, nb, bh);
    scan1_kernel<<<nb1, 1024, 0, stream>>>(bh, scanv, partials, L);
    scan2_kernel<<<1, 256, 0, stream>>>(partials, nb1);
    scan3_kernel<<<(L + 255) / 256, 256, 0, stream>>>(scanv, partials, L);
    p3_kernel<<<nb, 256, 0, stream>>>(src, dst, E, RE, nb, scanv, ebd, ebs);
    pb_kernel<<<2 * NBKT, 1024, 0, stream>>>(scanv, nb, RE, ebd, ebs,
                                             row_ptr, rs_in, rs_out, esrc);

    const int gb = (N + 63) / 64;   // 782
    const int ab = (N + 3) / 4;     // 12500

    // layer 1: Zcat = fused 3-relation aggregation of x; H = bsum1 + Zcat @ W1
    gather_kernel<false><<<ab, 256, 0, stream>>>(x, rs_in, rs_out, row_ptr, esrc, Z);
    gemmZ_kernel<128><<<dim3(gb, 2), 256, 0, stream>>>(Z, W1, bsum1, H);
    // layer 2: Zcat = fused aggregation of relu(H); out = bsum2 + Zcat @ W2
    gather_kernel<true><<<ab, 256, 0, stream>>>(H, rs_in, rs_out, row_ptr, esrc, Z);
    gemmZ_kernel<64><<<dim3(gb, 1), 256, 0, stream>>>(Z, W2, bsum2, out);
}

// Round 6
// 540.878 us; speedup vs baseline: 1.2572x; 1.2572x over previous
//
#include <hip/hip_runtime.h>
#include <hip/hip_fp16.h>

// RGCN: out = hetero(relu(hetero(x, W1,b1)), W2,b2)
// hetero(x) = sum_r [ Din_r^-1/2 A_r_sl Dout_r^-1/2 (x @ W_r) ] + sum_r b_r
// Aggregation commutes with @W_r: all relations gather from ONE feature buffer:
//   Z[n] = [ rs_in_r[n] * (sum_{e->n,r} rs_out_r[s_e]*feat[s_e] + rs_out_r[n]*feat[n]) ]_r
//   layer = bias + Z(N x 384) @ W(384 x WC)
// Round-5 lesson: gather is at the fabric floor (row-reads x row-bytes x ~50%
// L2-miss / 3.85 TB/s). Only levers: row BYTES and miss rate -> gather in fp16
// (halves requested bytes, halves working set). Per-edge coeff fp16-packed into
// esrc (kills the random rs_out[s] load). Zero global atomics in CSR build
// (round-3: device atomics cost ~32B fabric write each).

constexpr int N   = 50000;
constexpr int R   = 3;
constexpr int IN  = 128;
constexpr int HID = 128;
constexpr int OUT = 64;
constexpr int M   = R * N;                 // 150000 (rel,node) slots
constexpr int BK  = 1024;                  // keys per bucket
constexpr int NBKT = (M + BK - 1) / BK;    // 147 buckets
constexpr int CHUNK = 8192;                // edges per partition block

// ---- bias sums ----
__global__ void bsum_kernel(const float* __restrict__ b1, const float* __restrict__ b2,
                            float* __restrict__ bsum1, float* __restrict__ bsum2) {
    int t = threadIdx.x;
    if (t < HID) bsum1[t] = b1[t] + b1[HID + t] + b1[2 * HID + t];
    if (t < OUT) bsum2[t] = b2[t] + b2[OUT + t] + b2[2 * OUT + t];
}

// ---- fp32 -> fp16 convert (4 elems/thread) ----
__global__ void cvt_kernel(const float4* __restrict__ in, uint2* __restrict__ out16, int n4) {
    int i = blockIdx.x * 256 + threadIdx.x;
    if (i >= n4) return;
    float4 v = in[i];
    __half2 a = __floats2half2_rn(v.x, v.y);
    __half2 b = __floats2half2_rn(v.z, v.w);
    uint2 o;
    o.x = *(unsigned*)&a;
    o.y = *(unsigned*)&b;
    out16[i] = o;
}

// ---- P1: coarse bucket histograms per edge-chunk (dst-keyed and src-keyed) ----
__global__ __launch_bounds__(256) void p1_kernel(const int* __restrict__ src,
                                                 const int* __restrict__ dst,
                                                 int E, int RE, int nb,
                                                 int* __restrict__ bh) {
    __shared__ int hd[NBKT], hs[NBKT];
    for (int i = threadIdx.x; i < NBKT; i += 256) { hd[i] = 0; hs[i] = 0; }
    __syncthreads();
    int beg = blockIdx.x * CHUNK, end = min(RE, beg + CHUNK);
    for (int g = beg + (int)threadIdx.x; g < end; g += 256) {
        int rb = ((g >= E) + (g >= 2 * E)) * N;
        atomicAdd(&hd[(rb + dst[g]) >> 10], 1);
        atomicAdd(&hs[(rb + src[g]) >> 10], 1);
    }
    __syncthreads();
    for (int i = threadIdx.x; i < NBKT; i += 256) {
        bh[i * nb + blockIdx.x] = hd[i];
        bh[(NBKT + i) * nb + blockIdx.x] = hs[i];
    }
}

// ---- generic 3-stage exclusive scan over L ints ----
__global__ void scan1_kernel(const int* __restrict__ in, int* __restrict__ out,
                             int* __restrict__ partials, int L) {
    __shared__ int lds[1024];
    int t = threadIdx.x;
    int idx = blockIdx.x * 1024 + t;
    int v = (idx < L) ? in[idx] : 0;
    lds[t] = v;
    __syncthreads();
    for (int off = 1; off < 1024; off <<= 1) {
        int u = (t >= off) ? lds[t - off] : 0;
        __syncthreads();
        lds[t] += u;
        __syncthreads();
    }
    if (idx < L) out[idx] = lds[t] - v;
    if (t == 1023) partials[blockIdx.x] = lds[1023];
}

__global__ void scan2_kernel(int* __restrict__ partials, int nb1) {
    __shared__ int lds[256];
    int t = threadIdx.x;
    int v = (t < nb1) ? partials[t] : 0;
    lds[t] = v;
    __syncthreads();
    for (int off = 1; off < 256; off <<= 1) {
        int u = (t >= off) ? lds[t - off] : 0;
        __syncthreads();
        lds[t] += u;
        __syncthreads();
    }
    if (t < nb1) partials[t] = lds[t] - v;
}

__global__ void scan3_kernel(int* __restrict__ out, const int* __restrict__ partials, int L) {
    int i = blockIdx.x * 256 + threadIdx.x;
    if (i < L) out[i] += partials[i >> 10];
}

// ---- P3: scatter edges into bucket-sorted buffers via LDS cursors ----
__global__ __launch_bounds__(256) void p3_kernel(const int* __restrict__ src,
                                                 const int* __restrict__ dst,
                                                 int E, int RE, int nb,
                                                 const int* __restrict__ scanv,
                                                 int* __restrict__ ebd,
                                                 int* __restrict__ ebs) {
    __shared__ int cd[NBKT], cs[NBKT];
    for (int i = threadIdx.x; i < NBKT; i += 256) {
        cd[i] = scanv[i * nb + blockIdx.x];
        cs[i] = scanv[(NBKT + i) * nb + blockIdx.x] - RE;
    }
    __syncthreads();
    int beg = blockIdx.x * CHUNK, end = min(RE, beg + CHUNK);
    for (int g = beg + (int)threadIdx.x; g < end; g += 256) {
        int rb = ((g >= E) + (g >= 2 * E)) * N;
        int s  = src[g];
        int kd = rb + dst[g];
        int pd = atomicAdd(&cd[kd >> 10], 1);
        ebd[pd] = (s << 10) | (kd & 1023);
        int ks = rb + s;
        int ps = atomicAdd(&cs[ks >> 10], 1);
        ebs[ps] = ks & 1023;
    }
}

// ---- PB: per bucket — exact histogram -> row_ptr/rs, then CSR scatter ----
__global__ __launch_bounds__(1024) void pb_kernel(const int* __restrict__ scanv, int nb, int RE,
                                                  const int* __restrict__ ebd,
                                                  const int* __restrict__ ebs,
                                                  int* __restrict__ row_ptr,
                                                  float* __restrict__ rs_in,
                                                  float* __restrict__ rs_out,
                                                  int* __restrict__ esrc) {
    __shared__ int cnt[BK];
    __shared__ int cur[BK];
    int t = threadIdx.x;
    bool dside = blockIdx.x < NBKT;
    int k = dside ? blockIdx.x : blockIdx.x - NBKT;
    int half = dside ? 0 : NBKT;
    int segbeg = scanv[(half + k) * nb];
    int segend = (k == NBKT - 1) ? (dside ? RE : 2 * RE) : scanv[(half + k + 1) * nb];
    if (!dside) { segbeg -= RE; segend -= RE; }
    cnt[t] = 0;
    __syncthreads();
    const int* __restrict__ eb = dside ? ebd : ebs;
    for (int e = segbeg + t; e < segend; e += 1024)
        atomicAdd(&cnt[eb[e] & 1023], 1);
    __syncthreads();
    int slot = k * BK + t;
    int c = cnt[t];
    if (dside) {
        cur[t] = c;
        __syncthreads();
        for (int off = 1; off < 1024; off <<= 1) {
            int u = (t >= off) ? cur[t - off] : 0;
            __syncthreads();
            cur[t] += u;
            __syncthreads();
        }
        int excl = cur[t] - c;
        if (slot < M) {
            row_ptr[slot] = segbeg + excl;
            rs_in[slot] = rsqrtf((float)(c + 1));   // +1 self-loop
        }
        if (blockIdx.x == NBKT - 1 && t == 0) row_ptr[M] = RE;
        __syncthreads();
        cur[t] = segbeg + excl;
        __syncthreads();
        for (int e = segbeg + t; e < segend; e += 1024) {
            int v = eb[e];
            int pos = atomicAdd(&cur[v & 1023], 1);
            esrc[pos] = v >> 10;
        }
    } else {
        if (slot < M) rs_out[slot] = rsqrtf((float)(c + 1));
    }
}

// ---- pack per-edge coeff: esrc[i] = src | fp16(rs_out_r[src]) << 16 ----
__global__ void pack_kernel(unsigned int* __restrict__ esrc, const float* __restrict__ rs_out,
                            const int* __restrict__ row_ptr, int RE) {
    int i = blockIdx.x * 256 + threadIdx.x;
    if (i >= RE) return;
    int rp1 = row_ptr[N], rp2 = row_ptr[2 * N];
    int r = (i >= rp1) + (i >= rp2);
    unsigned s = esrc[i];
    __half h = __float2half_rn(rs_out[r * N + s]);
    esrc[i] = s | ((unsigned)__half_as_ushort(h) << 16);
}

// ---- fused 3-relation fp16 gather: one wave per node, half2/lane rows ----
__global__ __launch_bounds__(256) void gather_kernel(const __half2* __restrict__ X2,
                                                     const float* __restrict__ rs_in,
                                                     const float* __restrict__ rs_out,
                                                     const int* __restrict__ row_ptr,
                                                     const unsigned int* __restrict__ esrc,
                                                     __half2* __restrict__ Z2) {
    int n = blockIdx.x * 4 + (threadIdx.x >> 6);
    if (n >= N) return;
    int lane = threadIdx.x & 63;
    float2 xn = __half22float2(X2[(long)n * 64 + lane]);
#pragma unroll
    for (int r = 0; r < R; r++) {
        int key = r * N + n;
        float ax = 0.f, ay = 0.f;
        int beg = row_ptr[key], end = row_ptr[key + 1];
        int e = beg;
        for (; e + 4 <= end; e += 4) {
            unsigned u0 = esrc[e], u1 = esrc[e + 1], u2 = esrc[e + 2], u3 = esrc[e + 3];
            float c0 = __half2float(__ushort_as_half((unsigned short)(u0 >> 16)));
            float c1 = __half2float(__ushort_as_half((unsigned short)(u1 >> 16)));
            float c2 = __half2float(__ushort_as_half((unsigned short)(u2 >> 16)));
            float c3 = __half2float(__ushort_as_half((unsigned short)(u3 >> 16)));
            float2 y0 = __half22float2(X2[(long)(u0 & 0xffffu) * 64 + lane]);
            float2 y1 = __half22float2(X2[(long)(u1 & 0xffffu) * 64 + lane]);
            float2 y2 = __half22float2(X2[(long)(u2 & 0xffffu) * 64 + lane]);
            float2 y3 = __half22float2(X2[(long)(u3 & 0xffffu) * 64 + lane]);
            ax += c0 * y0.x + c1 * y1.x + c2 * y2.x + c3 * y3.x;
            ay += c0 * y0.y + c1 * y1.y + c2 * y2.y + c3 * y3.y;
        }
        for (; e < end; e++) {
            unsigned u = esrc[e];
            float c = __half2float(__ushort_as_half((unsigned short)(u >> 16)));
            float2 y = __half22float2(X2[(long)(u & 0xffffu) * 64 + lane]);
            ax += c * y.x; ay += c * y.y;
        }
        float cn = rs_out[key];                 // self-loop, fp32 coeff
        ax += cn * xn.x; ay += cn * xn.y;
        float ri = rs_in[key];
        Z2[(long)n * 192 + r * 64 + lane] = __floats2half2_rn(ri * ax, ri * ay);
    }
}

// ---- GEMM: out[N,WC] = bias + Z16[N,384] @ Wall[384,WC]; fp16 A staged->fp32 LDS.
// H16OUT: write fp16(relu(.)) to __half buffer; else fp32 with bias.
template <int WC, bool H16OUT>
__global__ __launch_bounds__(256) void gemmZ_kernel(const __half* __restrict__ Z16,
                                                    const float* __restrict__ Wall,
                                                    const float* __restrict__ bias,
                                                    void* __restrict__ outp) {
    __shared__ float sX[64 * 132];
    __shared__ float sW[128 * 64];
    int tid = threadIdx.x;
    int m0  = blockIdx.x * 64;
    int c0  = blockIdx.y * 64;
    int tx = tid & 15;
    int ty = tid >> 4;
    float4 acc[4];
#pragma unroll
    for (int i = 0; i < 4; i++) acc[i] = make_float4(0.f, 0.f, 0.f, 0.f);

    const uint2* Z4 = (const uint2*)Z16;   // 4 halves per uint2; row stride 96
    for (int kc = 0; kc < 384; kc += 128) {
        for (int j = tid; j < 64 * 32; j += 256) {
            int row = j >> 5, c4 = j & 31;
            uint2 u = make_uint2(0u, 0u);
            if (m0 + row < N) u = Z4[(long)(m0 + row) * 96 + (kc >> 2) + c4];
            __half2 h0 = *(__half2*)&u.x;
            __half2 h1 = *(__half2*)&u.y;
            float2 f0 = __half22float2(h0);
            float2 f1 = __half22float2(h1);
            *(float4*)&sX[row * 132 + c4 * 4] = make_float4(f0.x, f0.y, f1.x, f1.y);
        }
        for (int j = tid; j < 128 * 16; j += 256) {
            int k = j >> 4, c4 = j & 15;
            *(float4*)&sW[k * 64 + c4 * 4] = *(const float4*)&Wall[(long)(kc + k) * WC + c0 + c4 * 4];
        }
        __syncthreads();
        for (int k = 0; k < 128; k += 4) {
            float4 w0 = *(float4*)&sW[(k + 0) * 64 + tx * 4];
            float4 w1 = *(float4*)&sW[(k + 1) * 64 + tx * 4];
            float4 w2 = *(float4*)&sW[(k + 2) * 64 + tx * 4];
            float4 w3 = *(float4*)&sW[(k + 3) * 64 + tx * 4];
#pragma unroll
            for (int i = 0; i < 4; i++) {
                float4 xv = *(float4*)&sX[(ty * 4 + i) * 132 + k];
                acc[i].x += xv.x * w0.x + xv.y * w1.x + xv.z * w2.x + xv.w * w3.x;
                acc[i].y += xv.x * w0.y + xv.y * w1.y + xv.z * w2.y + xv.w * w3.y;
                acc[i].z += xv.x * w0.z + xv.y * w1.z + xv.z * w2.z + xv.w * w3.z;
                acc[i].w += xv.x * w0.w + xv.y * w1.w + xv.z * w2.w + xv.w * w3.w;
            }
        }
        __syncthreads();
    }
    float4 b4 = *(const float4*)&bias[c0 + tx * 4];
#pragma unroll
    for (int i = 0; i < 4; i++) {
        int row = m0 + ty * 4 + i;
        if (row < N) {
            float4 a = acc[i];
            a.x += b4.x; a.y += b4.y; a.z += b4.z; a.w += b4.w;
            if (H16OUT) {
                a.x = fmaxf(a.x, 0.f); a.y = fmaxf(a.y, 0.f);
                a.z = fmaxf(a.z, 0.f); a.w = fmaxf(a.w, 0.f);
                __half2 h0 = __floats2half2_rn(a.x, a.y);
                __half2 h1 = __floats2half2_rn(a.z, a.w);
                uint2 o;
                o.x = *(unsigned*)&h0;
                o.y = *(unsigned*)&h1;
                *(uint2*)((__half*)outp + (long)row * WC + c0 + tx * 4) = o;
            } else {
                *(float4*)((float*)outp + (long)row * WC + c0 + tx * 4) = a;
            }
        }
    }
}

extern "C" void kernel_launch(void* const* d_in, const int* in_sizes, int n_in,
                              void* d_out, int out_size, void* d_ws, size_t ws_size,
                              hipStream_t stream) {
    const float* x  = (const float*)d_in[0];
    const int*  src = (const int*)d_in[1];
    const int*  dst = (const int*)d_in[2];
    const float* W1 = (const float*)d_in[3];   // [3][128][128] == [384][128]
    const float* b1 = (const float*)d_in[4];
    const float* W2 = (const float*)d_in[5];   // [3][128][64]  == [384][64]
    const float* b2 = (const float*)d_in[6];
    float* out = (float*)d_out;
    const int E  = in_sizes[1] / R;
    const int RE = in_sizes[1];
    const int nb = (RE + CHUNK - 1) / CHUNK;
    const int L  = 2 * NBKT * nb;
    const int nb1 = (L + 1023) / 1024;

    char* ws = (char*)d_ws;
    size_t off = 0;
    auto alloc = [&](size_t bytes) -> void* {
        void* p = ws + off;
        off += (bytes + 255) & ~(size_t)255;
        return p;
    };
    float* bsum1    = (float*)alloc(HID * 4);
    float* bsum2    = (float*)alloc(OUT * 4);
    float* rs_in    = (float*)alloc((size_t)M * 4);
    float* rs_out   = (float*)alloc((size_t)M * 4);
    int*   row_ptr  = (int*)alloc((size_t)(M + 1) * 4);
    int*   bh       = (int*)alloc((size_t)L * 4);
    int*   scanv    = (int*)alloc((size_t)L * 4);
    int*   partials = (int*)alloc((size_t)nb1 * 4);
    int*   esrc     = (int*)alloc((size_t)RE * 4);
    // region A: ebd+ebs (19.2MB) during build, Z16 (38.4MB) afterwards
    char*  regA     = (char*)alloc((size_t)N * 384 * 2);
    int*   ebd      = (int*)regA;
    int*   ebs      = (int*)(regA + (size_t)RE * 4);
    __half* Z16     = (__half*)regA;
    __half* x16     = (__half*)alloc((size_t)N * IN * 2);
    __half* H16     = (__half*)alloc((size_t)N * HID * 2);

    bsum_kernel<<<1, 128, 0, stream>>>(b1, b2, bsum1, bsum2);
    cvt_kernel<<<(N * IN / 4 + 255) / 256, 256, 0, stream>>>(
        (const float4*)x, (uint2*)x16, N * IN / 4);
    p1_kernel<<<nb, 256, 0, stream>>>(src, dst, E, RE, nb, bh);
    scan1_kernel<<<nb1, 1024, 0, stream>>>(bh, scanv, partials, L);
    scan2_kernel<<<1, 256, 0, stream>>>(partials, nb1);
    scan3_kernel<<<(L + 255) / 256, 256, 0, stream>>>(scanv, partials, L);
    p3_kernel<<<nb, 256, 0, stream>>>(src, dst, E, RE, nb, scanv, ebd, ebs);
    pb_kernel<<<2 * NBKT, 1024, 0, stream>>>(scanv, nb, RE, ebd, ebs,
                                             row_ptr, rs_in, rs_out, esrc);
    pack_kernel<<<(RE + 255) / 256, 256, 0, stream>>>(
        (unsigned int*)esrc, rs_out, row_ptr, RE);

    const int gb = (N + 63) / 64;   // 782
    const int ab = (N + 3) / 4;     // 12500

    // layer 1: Z = fused aggregation of x16; H16 = fp16(relu(bsum1 + Z @ W1))
    gather_kernel<<<ab, 256, 0, stream>>>((const __half2*)x16, rs_in, rs_out,
                                          row_ptr, (const unsigned int*)esrc,
                                          (__half2*)Z16);
    gemmZ_kernel<128, true><<<dim3(gb, 2), 256, 0, stream>>>(Z16, W1, bsum1, H16);
    // layer 2: Z = fused aggregation of H16; out = bsum2 + Z @ W2
    gather_kernel<<<ab, 256, 0, stream>>>((const __half2*)H16, rs_in, rs_out,
                                          row_ptr, (const unsigned int*)esrc,
                                          (__half2*)Z16);
    gemmZ_kernel<64, false><<<dim3(gb, 1), 256, 0, stream>>>(Z16, W2, bsum2, out);
}